// Round 3
// baseline (469.837 us; speedup 1.0000x reference)
//
#include <hip/hip_runtime.h>
#include <hip/hip_fp16.h>
#include <math.h>

// CapsuleLayer dynamic routing, fp32, MI355X (gfx950).
// B=64, IN_CAPS=2048, IN_DIM=8, OUT_CAPS=32, OUT_DIM=16, 3 routing iters.
//
// b_ij after r updates = u_hat_i . (v0+...+v_{r-1}) (b starts at 0) -> no
// u_hat materialization; each pass recomputes it from W.
//
// R2 -> R3 (LDS-wall + occupancy fix):
//  * Wave keeps a full W-fragment (64 floats -> 64 VGPRs) loaded ONCE per i
//    and amortizes it over NB=8 batch elements (R2 re-read the tile from LDS
//    every iteration: ~20 us/pass of pure LDS-pipe time).
//  * x comes via wave-uniform (scalarized) loads, v-sum via one coalesced
//    fp16 table load per (b,i) -> zero per-FMA LDS traffic.
//  * Softmax reduction moved off the LDS pipe: DPP rotate-butterfly
//    (4 v_add_f32_dpp) + 2 shuffles instead of 6 ds_swizzles.
//  * Grid 512 -> 1024 blocks (BG=4 x ISTR=256), 33 KB LDS, lb(256,3).
//  * fp16 v-sum table: bp abs error ~2e-4, ~4x under the 9.6e-4 threshold.

#define IC 2048
#define OC 32
#define OD 16
#define B_N 64
#define S_ELEMS (B_N * OC * OD)   // 32768
#define BPB 16                    // b per block
#define BG  (B_N / BPB)           // 4
#define IPB 8                     // i per block
#define ISTR (IC / IPB)           // 256 partial slots
#define NB  8                     // b per wave
#define NSTEP 4                   // i-steps per block (2 i staged per step)

// DPP rotate-butterfly add within 16-lane rows: ror 8,4,2,1 leaves the
// row-sum in every lane; one xor-16 shuffle then combines the two rows of a
// 32-lane (o) group. All VALU except the final shuffle.
template <int CTRL>
__device__ __forceinline__ float dpp_add(float v) {
    int r = __builtin_amdgcn_update_dpp(0, __float_as_int(v), CTRL, 0xf, 0xf, true);
    return v + __int_as_float(r);
}

// Lane map: o = lane&31, jh = lane>>5 (j = jh*8+jj). Waves: ipar = w&1 (which
// staged i), bh = w>>1 (which 8 b's). LDS W layout: WS[il*2+dh][jj][65 chunks]
// with chunk = (o<<1)|jh -> fragment reads are stride-1 float4 across lanes
// (conflict-free); +1 pad spreads staging-write banks.

template <int FIRST>
__launch_bounds__(256, 3)
__global__ void caps_pass(const float* __restrict__ Wg,
                          const float* __restrict__ xg,
                          const __half* __restrict__ vhg,
                          float* __restrict__ part)
{
    __shared__ float4 WS[4 * 8 * 65];          // 2080 float4 = 33280 B
    float* accred = (float*)WS;                // epilogue overlay: 16*520 floats

    const int tid  = threadIdx.x;
    const int lane = tid & 63;
    const int w    = tid >> 6;
    const int o    = lane & 31;
    const int jh   = lane >> 5;
    const int chunk = (o << 1) | jh;
    const int ipar = w & 1;
    const int bh   = w >> 1;

    const int is   = blockIdx.x & (ISTR - 1);  // same-is blocks 256 apart -> same XCD
    const int bg   = blockIdx.x >> 8;          // 0..3
    const int bblk = bg * BPB;
    const int bq   = bblk + bh * 8;            // wave's first b

    const float4* wq = (const float4*)Wg;

    float acc[NB][8];
#pragma unroll
    for (int n = 0; n < NB; ++n)
#pragma unroll
        for (int jj = 0; jj < 8; ++jj) acc[n][jj] = 0.0f;

    for (int step = 0; step < NSTEP; ++step) {
        if (step) __syncthreads();             // everyone done reading WS
        // ---- stage 2 i's (32 KB) coalesced, deswizzled
        {
            const size_t base = (size_t)(is * IPB + step * 2) * 1024;  // quad idx
#pragma unroll
            for (int q = 0; q < 8; ++q) {
                const int G = q * 256 + tid;       // 0..2047
                const float4 val = wq[base + G];
                const int il = G >> 10;
                const int r  = G & 1023;           // = o*32 + j*2 + dh
                const int oo = r >> 5;
                const int j  = (r >> 1) & 15;
                const int dh = r & 1;
                WS[((il * 2 + dh) * 8 + (j & 7)) * 65 + ((oo << 1) | (j >> 3))] = val;
            }
        }
        __syncthreads();                       // stage visible

        // ---- W fragment -> 64 VGPRs (16 conflict-free ds_read_b128)
        float4 fr[2][8];
#pragma unroll
        for (int dh = 0; dh < 2; ++dh)
#pragma unroll
            for (int jj = 0; jj < 8; ++jj)
                fr[dh][jj] = WS[((ipar * 2 + dh) * 8 + jj) * 65 + chunk];

        const int i_g = __builtin_amdgcn_readfirstlane(is * IPB + step * 2 + ipar);

        // ---- b loop: 8 b's reuse the fragment
#pragma unroll
        for (int n = 0; n < NB; ++n) {
            const int b_s = __builtin_amdgcn_readfirstlane(bq + n);
            const float4* xp = (const float4*)(xg + ((size_t)b_s * IC + i_g) * 8);
            const float4 xa = xp[0];
            const float4 xb = xp[1];

            float u[8];
#pragma unroll
            for (int jj = 0; jj < 8; ++jj) {
                float t = fr[0][jj].x * xa.x;
                t = fmaf(fr[0][jj].y, xa.y, t);
                t = fmaf(fr[0][jj].z, xa.z, t);
                t = fmaf(fr[0][jj].w, xa.w, t);
                t = fmaf(fr[1][jj].x, xb.x, t);
                t = fmaf(fr[1][jj].y, xb.y, t);
                t = fmaf(fr[1][jj].z, xb.z, t);
                t = fmaf(fr[1][jj].w, xb.w, t);
                u[jj] = t;
            }

            float c;
            if (FIRST) {
                c = 1.0f;   // softmax(0)=1/32 folded into epilogue scale
            } else {
                // coalesced fp16 v-sum fragment: vh[b][jh][o][jj]
                const float4 hvv = *(const float4*)(vhg + (size_t)(bq + n) * 512 + jh * 256 + o * 8);
                const __half2* hp = (const __half2*)&hvv;
                float bp = u[0] * __low2float(hp[0]);
                bp = fmaf(u[1], __high2float(hp[0]), bp);
                bp = fmaf(u[2], __low2float(hp[1]), bp);
                bp = fmaf(u[3], __high2float(hp[1]), bp);
                bp = fmaf(u[4], __low2float(hp[2]), bp);
                bp = fmaf(u[5], __high2float(hp[2]), bp);
                bp = fmaf(u[6], __low2float(hp[3]), bp);
                bp = fmaf(u[7], __high2float(hp[3]), bp);
                bp += __shfl_xor(bp, 32);          // combine j-halves
                const float e = __expf(bp);        // logits tiny; no max needed
                float se = e;
                se = dpp_add<0x128>(se);           // row_ror:8
                se = dpp_add<0x124>(se);           // row_ror:4
                se = dpp_add<0x122>(se);           // row_ror:2
                se = dpp_add<0x121>(se);           // row_ror:1
                se += __shfl_xor(se, 16);          // combine the two 16-rows
                c = e * __builtin_amdgcn_rcpf(se);
            }
#pragma unroll
            for (int jj = 0; jj < 8; ++jj)
                acc[n][jj] = fmaf(c, u[jj], acc[n][jj]);
        }
    }

    // ---- epilogue: combine ipar pairs in LDS, store coalesced partials
    __syncthreads();
    if (ipar == 0) {
#pragma unroll
        for (int n = 0; n < NB; ++n)
#pragma unroll
            for (int jj = 0; jj < 8; ++jj)
                accred[(bh * 8 + n) * 520 + jj * 64 + chunk] = acc[n][jj];
    }
    __syncthreads();
    if (ipar == 1) {
#pragma unroll
        for (int n = 0; n < NB; ++n)
#pragma unroll
            for (int jj = 0; jj < 8; ++jj)
                accred[(bh * 8 + n) * 520 + jj * 64 + chunk] += acc[n][jj];
    }
    __syncthreads();
    const float scale = FIRST ? (1.0f / 32.0f) : 1.0f;
    float* dst = part + (size_t)is * S_ELEMS + (size_t)bblk * 512;
#pragma unroll
    for (int k = 0; k < 32; ++k) {
        const int e  = k * 256 + tid;          // 0..8191 block-local [b][o][j]
        const int bl = e >> 9;
        const int oo = (e >> 4) & 31;
        const int j  = e & 15;
        dst[e] = accred[bl * 520 + (j & 7) * 64 + oo * 2 + (j >> 3)] * scale;
    }
}

// Fused 256-way partial reduction + squash. 512 blocks x 256; 4 k-slices.
// MODE 0: vsum = v   MODE 1: vsum += v   MODE 2: out = v
template <int MODE>
__global__ void caps_reduce(const float* __restrict__ part,
                            float* __restrict__ vsum,
                            __half* __restrict__ vh,
                            float* __restrict__ out)
{
    __shared__ float red[256];
    const int tid = threadIdx.x;
    const int e   = blockIdx.x * 64 + (tid & 63);
    const int ks  = tid >> 6;                  // 0..3
    float s = 0.0f;
#pragma unroll 8
    for (int m = 0; m < 64; ++m)
        s += part[(size_t)(ks * 64 + m) * S_ELEMS + e];
    red[tid] = s;
    __syncthreads();
    if (tid < 64) {
        s = red[tid] + red[tid + 64] + red[tid + 128] + red[tid + 192];
        float s2 = s * s;                      // ||s||^2 over 16-lane j-group
        s2 += __shfl_xor(s2, 1);
        s2 += __shfl_xor(s2, 2);
        s2 += __shfl_xor(s2, 4);
        s2 += __shfl_xor(s2, 8);
        const float v = s * (s2 / ((1.0f + s2) * sqrtf(s2 + 1e-9f)));
        if (MODE == 2) {
            out[e] = v;
        } else {
            const float nv = (MODE == 0) ? v : vsum[e] + v;
            vsum[e] = nv;
            // fp16 table in pass-kernel layout [b][jh][o][jj]
            const int b = e >> 9, oo = (e >> 4) & 31, j = e & 15;
            vh[(size_t)b * 512 + (j >> 3) * 256 + oo * 8 + (j & 7)] = __float2half(nv);
        }
    }
}

extern "C" void kernel_launch(void* const* d_in, const int* in_sizes, int n_in,
                              void* d_out, int out_size, void* d_ws, size_t ws_size,
                              hipStream_t stream)
{
    const float* x = (const float*)d_in[0];   // [64, 2048, 8]
    const float* W = (const float*)d_in[1];   // [1, 2048, 32, 16, 8]
    float* out = (float*)d_out;               // [64, 32, 16]

    float*  part = (float*)d_ws;                         // 256*32768 = 33.5 MB
    float*  vsum = part + (size_t)ISTR * S_ELEMS;        // 32768 floats
    __half* vh   = (__half*)(vsum + S_ELEMS);            // 32768 halves

    const dim3 g(BG * ISTR);       // 1024
    const dim3 b(256);
    const dim3 rg(S_ELEMS / 64);   // 512

    caps_pass<1><<<g, b, 0, stream>>>(W, x, nullptr, part);
    caps_reduce<0><<<rg, b, 0, stream>>>(part, vsum, vh, out);  // vsum = v0
    caps_pass<0><<<g, b, 0, stream>>>(W, x, vh, part);
    caps_reduce<1><<<rg, b, 0, stream>>>(part, vsum, vh, out);  // vsum = v0+v1
    caps_pass<0><<<g, b, 0, stream>>>(W, x, vh, part);
    caps_reduce<2><<<rg, b, 0, stream>>>(part, vsum, vh, out);  // out = v2
}

// Round 4
// 265.826 us; speedup vs baseline: 1.7675x; 1.7675x over previous
//
#include <hip/hip_runtime.h>
#include <math.h>

// CapsuleLayer dynamic routing, fp32, MI355X (gfx950).
// B=64, IN_CAPS=2048, IN_DIM=8, OUT_CAPS=32, OUT_DIM=16, 3 routing iters.
//
// b_ij after r updates = u_hat_i . (v0+...+v_{r-1}) (b starts at 0) -> no
// u_hat materialization; each pass recomputes it from W via LDS staging.
//
// R3 post-mortem: per-(b,i) GLOBAL reads (fp16 vsum table) missed L2 (evicted
// by the partials stream) and serialized -> 173 us/pass at 9% VALUBusy.
// R4 = R2 skeleton (45.5 us/pass) with surgical fixes:
//  * NB=8 b's per wave (W-fragment LDS reads per (b,i) halved) with vsum in
//    fp32 VGPRs (loaded once/wave) and x via LDS broadcast -- hot loop touches
//    registers + LDS only.
//  * IPB=8, BPB=32, grid 512 (2 blocks/CU, 8 waves/CU), ONE barrier per i.
//  * Softmax row-sums via DPP (VALU pipe) instead of ds_swizzle.
//  * lb(256,2): 256-VGPR budget so frag(64)+acc(64)+vsum(64) stay live.

#define IC 2048
#define OC 32
#define OD 16
#define B_N 64
#define S_ELEMS (B_N * OC * OD)   // 32768
#define IPB 8                     // i per block
#define ISTR (IC / IPB)           // 256 partial slots
#define BPB 32                    // b per block
#define BG  (B_N / BPB)           // 2
#define NB  8                     // b per wave

// DPP rotate-add within 16-lane rows: ror 8,4,2,1 leaves the row-sum in
// every lane of the row. VALU-pipe, no LDS.
template <int CTRL>
__device__ __forceinline__ float dpp_add(float v) {
    int r = __builtin_amdgcn_update_dpp(0, __float_as_int(v), CTRL, 0xf, 0xf, true);
    return v + __int_as_float(r);
}

// Lane map: o = lane&31, jh = lane>>5 (j = jh*8+jj). Wave w owns b's
// bq..bq+7 (disjoint across waves -> no cross-wave epilogue reduction).
// LDS W tile layout (per parity): WS[(dh*8+jj)*65 + c], c = (o<<1)|jh.
// Fragment reads: for fixed (dh,jj), lanes read 64 contiguous float4
// (balanced banks); ROWQ=65 spreads the staging-write banks.

template <int FIRST>
__launch_bounds__(256, 2)
__global__ void caps_pass(const float* __restrict__ Wg,
                          const float* __restrict__ xg,
                          const float* __restrict__ vs,
                          float* __restrict__ part)
{
    __shared__ float4 WS[2][16 * 65];   // 2 x 16.6 KB
    __shared__ float4 XS[2][64];        // 2 x 1 KB  (32 b x 8 floats)

    const int tid  = threadIdx.x;
    const int lane = tid & 63;
    const int w    = tid >> 6;
    const int o    = lane & 31;
    const int jh   = lane >> 5;
    const int c    = (o << 1) | jh;

    const int is   = blockIdx.x & (ISTR - 1);  // same-is pair 256 apart -> same XCD
    const int bg   = blockIdx.x >> 8;          // 0..1
    const int bblk = bg * BPB;
    const int bq   = bblk + w * NB;            // wave's first b

    const float4* wq = (const float4*)Wg;
    const float4* xq = (const float4*)xg;

    // v-sum fragments: fp32, registers, loaded once per wave (64 VGPRs)
    float4 va[NB], vb[NB];
    if (!FIRST) {
#pragma unroll
        for (int n = 0; n < NB; ++n) {
            const float4* vp = (const float4*)(vs + (size_t)(bq + n) * 512 + o * 16 + jh * 8);
            va[n] = vp[0];
            vb[n] = vp[1];
        }
    }

    float acc[NB][8];
#pragma unroll
    for (int n = 0; n < NB; ++n)
#pragma unroll
        for (int jj = 0; jj < 8; ++jj) acc[n][jj] = 0.0f;

    // ---- prologue: stage i0 into parity 0
    {
        const size_t base = (size_t)(is * IPB) * 1024;
#pragma unroll
        for (int q = 0; q < 4; ++q) {
            const int G = q * 256 + tid;                 // 0..1023 quad in tile
            const float4 val = wq[base + G];
            const int oo = G >> 5, j = (G >> 1) & 15, dh = G & 1;
            WS[0][((dh << 3) | (j & 7)) * 65 + ((oo << 1) | (j >> 3))] = val;
        }
        if (tid < 64)
            XS[0][tid] = xq[((size_t)(bblk + (tid >> 1)) * IC + is * IPB) * 2 + (tid & 1)];
    }

    for (int il = 0; il < IPB; ++il) {
        const int p = il & 1;
        __syncthreads();   // stage(il) visible; all waves done reading p^1

        // issue next tile's global loads (latency hidden under compute)
        float4 g0 = {}, g1 = {}, g2 = {}, g3 = {}, gx = {};
        const bool more = (il + 1 < IPB);
        if (more) {
            const size_t base = (size_t)(is * IPB + il + 1) * 1024;
            g0 = wq[base + 0 * 256 + tid];
            g1 = wq[base + 1 * 256 + tid];
            g2 = wq[base + 2 * 256 + tid];
            g3 = wq[base + 3 * 256 + tid];
            if (tid < 64)
                gx = xq[((size_t)(bblk + (tid >> 1)) * IC + is * IPB + il + 1) * 2 + (tid & 1)];
        }

        // W fragment -> 64 VGPRs (16 balanced ds_read_b128), reused by 8 b's
        float4 fr0[8], fr1[8];
#pragma unroll
        for (int jj = 0; jj < 8; ++jj) {
            fr0[jj] = WS[p][jj * 65 + c];
            fr1[jj] = WS[p][(8 + jj) * 65 + c];
        }

#pragma unroll
        for (int n = 0; n < NB; ++n) {
            const float4 xa = XS[p][(w * NB + n) * 2];       // broadcast reads
            const float4 xb = XS[p][(w * NB + n) * 2 + 1];

            float u[8];
#pragma unroll
            for (int jj = 0; jj < 8; ++jj) {
                float t = fr0[jj].x * xa.x;
                t = fmaf(fr0[jj].y, xa.y, t);
                t = fmaf(fr0[jj].z, xa.z, t);
                t = fmaf(fr0[jj].w, xa.w, t);
                t = fmaf(fr1[jj].x, xb.x, t);
                t = fmaf(fr1[jj].y, xb.y, t);
                t = fmaf(fr1[jj].z, xb.z, t);
                t = fmaf(fr1[jj].w, xb.w, t);
                u[jj] = t;
            }

            float cc;
            if (FIRST) {
                cc = 1.0f;   // softmax(0)=1/32 folded into epilogue scale
            } else {
                float bp = u[0] * va[n].x;
                bp = fmaf(u[1], va[n].y, bp);
                bp = fmaf(u[2], va[n].z, bp);
                bp = fmaf(u[3], va[n].w, bp);
                bp = fmaf(u[4], vb[n].x, bp);
                bp = fmaf(u[5], vb[n].y, bp);
                bp = fmaf(u[6], vb[n].z, bp);
                bp = fmaf(u[7], vb[n].w, bp);
                bp += __shfl_xor(bp, 32);          // combine j-halves
                const float e = __expf(bp);        // logits tiny; no max needed
                float se = e;
                se = dpp_add<0x128>(se);           // row_ror:8
                se = dpp_add<0x124>(se);           // row_ror:4
                se = dpp_add<0x122>(se);           // row_ror:2
                se = dpp_add<0x121>(se);           // row_ror:1
                se += __shfl_xor(se, 16);          // combine the two 16-rows
                cc = e * __builtin_amdgcn_rcpf(se);
            }
#pragma unroll
            for (int jj = 0; jj < 8; ++jj)
                acc[n][jj] = fmaf(cc, u[jj], acc[n][jj]);
        }

        // drain staged tile into the other parity (safe: top barrier of this
        // iteration guaranteed everyone finished reading p^1)
        if (more) {
            auto put = [&](int G, float4 val) {
                const int oo = G >> 5, j = (G >> 1) & 15, dh = G & 1;
                WS[p ^ 1][((dh << 3) | (j & 7)) * 65 + ((oo << 1) | (j >> 3))] = val;
            };
            put(0 * 256 + tid, g0);
            put(1 * 256 + tid, g1);
            put(2 * 256 + tid, g2);
            put(3 * 256 + tid, g3);
            if (tid < 64) XS[p ^ 1][tid] = gx;
        }
    }

    // ---- epilogue: waves own disjoint b's -> direct coalesced stores
    const float scale = FIRST ? (1.0f / 32.0f) : 1.0f;
#pragma unroll
    for (int n = 0; n < NB; ++n) {
        float* dst = part + (size_t)is * S_ELEMS + (size_t)(bq + n) * 512 + o * 16 + jh * 8;
        float4 lo = {acc[n][0] * scale, acc[n][1] * scale, acc[n][2] * scale, acc[n][3] * scale};
        float4 hi = {acc[n][4] * scale, acc[n][5] * scale, acc[n][6] * scale, acc[n][7] * scale};
        ((float4*)dst)[0] = lo;
        ((float4*)dst)[1] = hi;
    }
}

// Fused 256-way partial reduction + squash, all fp32.
// MODE 0: vsum = v   MODE 1: vsum += v   MODE 2: out = v
template <int MODE>
__global__ void caps_reduce(const float* __restrict__ part,
                            float* __restrict__ vsum,
                            float* __restrict__ out)
{
    __shared__ float red[256];
    const int tid = threadIdx.x;
    const int e   = blockIdx.x * 64 + (tid & 63);   // (b,o,j) element
    const int ks  = tid >> 6;                       // k-slice 0..3
    float s = 0.0f;
#pragma unroll 8
    for (int m = 0; m < 64; ++m)
        s += part[(size_t)(ks * 64 + m) * S_ELEMS + e];
    red[tid] = s;
    __syncthreads();
    if (tid < 64) {
        s = red[tid] + red[tid + 64] + red[tid + 128] + red[tid + 192];
        float s2 = s * s;                           // ||s||^2 over 16-j group
        s2 += __shfl_xor(s2, 1);
        s2 += __shfl_xor(s2, 2);
        s2 += __shfl_xor(s2, 4);
        s2 += __shfl_xor(s2, 8);
        const float v = s * (s2 / ((1.0f + s2) * sqrtf(s2 + 1e-9f)));
        if (MODE == 2)      out[e] = v;
        else if (MODE == 0) vsum[e] = v;
        else                vsum[e] += v;
    }
}

extern "C" void kernel_launch(void* const* d_in, const int* in_sizes, int n_in,
                              void* d_out, int out_size, void* d_ws, size_t ws_size,
                              hipStream_t stream)
{
    const float* x = (const float*)d_in[0];   // [64, 2048, 8]
    const float* W = (const float*)d_in[1];   // [1, 2048, 32, 16, 8]
    float* out = (float*)d_out;               // [64, 32, 16]

    float* part = (float*)d_ws;                    // 256 x 32768 x 4 B = 33.5 MB
    float* vsum = part + (size_t)ISTR * S_ELEMS;   // 32768 floats

    const dim3 g(BG * ISTR);       // 512 blocks
    const dim3 b(256);
    const dim3 rg(S_ELEMS / 64);   // 512 blocks

    caps_pass<1><<<g, b, 0, stream>>>(W, x, nullptr, part);
    caps_reduce<0><<<rg, b, 0, stream>>>(part, vsum, out);   // vsum = v0
    caps_pass<0><<<g, b, 0, stream>>>(W, x, vsum, part);
    caps_reduce<1><<<rg, b, 0, stream>>>(part, vsum, out);   // vsum = v0+v1
    caps_pass<0><<<g, b, 0, stream>>>(W, x, vsum, part);
    caps_reduce<2><<<rg, b, 0, stream>>>(part, vsum, out);   // out = v2
}

// Round 6
// 197.035 us; speedup vs baseline: 2.3845x; 1.3491x over previous
//
#include <hip/hip_runtime.h>
#include <math.h>

// CapsuleLayer dynamic routing, fp32, MI355X (gfx950).
// B=64, IN_CAPS=2048, IN_DIM=8, OUT_CAPS=32, OUT_DIM=16, 3 routing iters.
//
// b_ij after r updates = u_hat_i . (v0+...+v_{r-1}) (b starts at 0) -> no
// u_hat materialization; each pass recomputes it from W via LDS staging.
//
// R4 post-mortem (80.6 us/pass, VALU 17.9%, FETCH 97 MB, WRITE 71.7 MB):
//  (a) strided 16B-per-32B epilogue stores -> sector write amplification
//      (WRITE 2.14x partials) + write-allocate fetches; backend-bound.
//  (b) VGPR_Count=128 (lb(256,2) heuristic) -> compiler sank the W-fragment
//      ds_reads into the n-loop: LDS reads x8 per i, defeating NB=8 reuse.
// R5/R6 fixes exactly these:
//  * lb(256,1): 512-VGPR budget so acc(64)+vsum(64)+frag(64) stay live.
//  * Dense epilogue: acc -> LDS overlay -> tid-contiguous float4 stores
//    (full 128B lines), 2 phases of 16 b. Nontemporal on the partials
//    stream (both store here and load in reduce) to keep W/x/vsum in L2.
//  * (R6) nontemporal builtins need native clang vector types, not HIP float4.

#define IC 2048
#define OC 32
#define OD 16
#define B_N 64
#define S_ELEMS (B_N * OC * OD)   // 32768
#define IPB 8                     // i per block
#define ISTR (IC / IPB)           // 256 partial slots
#define BPB 32                    // b per block
#define BG  (B_N / BPB)           // 2
#define NB  8                     // b per wave

typedef float nt4 __attribute__((ext_vector_type(4)));   // nontemporal-legal

// DPP rotate-add within 16-lane rows: ror 8,4,2,1 leaves the row-sum in
// every lane of the row. VALU-pipe, no LDS.
template <int CTRL>
__device__ __forceinline__ float dpp_add(float v) {
    int r = __builtin_amdgcn_update_dpp(0, __float_as_int(v), CTRL, 0xf, 0xf, true);
    return v + __int_as_float(r);
}

// Lane map: o = lane&31, jh = lane>>5 (j = jh*8+jj), chunk c = (o<<1)|jh.
// Wave w owns b's bq..bq+7 (disjoint across waves).
// LDS W tile (per parity): WS[(dh*8+jj)*65 + c] -> fragment reads for fixed
// (dh,jj) are 64 contiguous float4 across lanes (bank-balanced); the 65
// stride spreads staging-write banks.

template <int FIRST>
__launch_bounds__(256, 1)
__global__ void caps_pass(const float* __restrict__ Wg,
                          const float* __restrict__ xg,
                          const float* __restrict__ vs,
                          float* __restrict__ part)
{
    __shared__ float4 WS[2][16 * 65];   // 33.3 KB (epilogue overlays this)
    __shared__ float4 XS[2][64];        // 2 KB (32 b x 8 floats, x2 parity)
    float* accred = (float*)WS;         // epilogue: 16 b x 520 floats = 33.3 KB

    const int tid  = threadIdx.x;
    const int lane = tid & 63;
    const int w    = tid >> 6;
    const int o    = lane & 31;
    const int jh   = lane >> 5;
    const int c    = (o << 1) | jh;

    const int is   = blockIdx.x & (ISTR - 1);  // same-is pair 256 apart -> same XCD
    const int bg   = blockIdx.x >> 8;          // 0..1
    const int bblk = bg * BPB;
    const int bq   = bblk + w * NB;            // wave's first b

    const float4* wq = (const float4*)Wg;
    const float4* xq = (const float4*)xg;

    // v-sum fragments: fp32 registers, loaded once per wave (64 VGPRs)
    float4 va[NB], vb[NB];
    if (!FIRST) {
#pragma unroll
        for (int n = 0; n < NB; ++n) {
            const float4* vp = (const float4*)(vs + (size_t)(bq + n) * 512 + o * 16 + jh * 8);
            va[n] = vp[0];
            vb[n] = vp[1];
        }
    }

    float acc[NB][8];
#pragma unroll
    for (int n = 0; n < NB; ++n)
#pragma unroll
        for (int jj = 0; jj < 8; ++jj) acc[n][jj] = 0.0f;

    // ---- prologue: stage i0 into parity 0
    {
        const size_t base = (size_t)(is * IPB) * 1024;
#pragma unroll
        for (int q = 0; q < 4; ++q) {
            const int G = q * 256 + tid;                 // quad index in tile
            const float4 val = wq[base + G];
            const int oo = G >> 5, j = (G >> 1) & 15, dh = G & 1;
            WS[0][((dh << 3) | (j & 7)) * 65 + ((oo << 1) | (j >> 3))] = val;
        }
        if (tid < 64)
            XS[0][tid] = xq[((size_t)(bblk + (tid >> 1)) * IC + is * IPB) * 2 + (tid & 1)];
    }

    for (int il = 0; il < IPB; ++il) {
        const int p = il & 1;
        __syncthreads();   // stage(il) visible; all waves done reading p^1

        // issue next tile's global loads (latency hidden under compute)
        float4 g0 = {}, g1 = {}, g2 = {}, g3 = {}, gx = {};
        const bool more = (il + 1 < IPB);
        if (more) {
            const size_t base = (size_t)(is * IPB + il + 1) * 1024;
            g0 = wq[base + 0 * 256 + tid];
            g1 = wq[base + 1 * 256 + tid];
            g2 = wq[base + 2 * 256 + tid];
            g3 = wq[base + 3 * 256 + tid];
            if (tid < 64)
                gx = xq[((size_t)(bblk + (tid >> 1)) * IC + is * IPB + il + 1) * 2 + (tid & 1)];
        }

        // W fragment -> 64 VGPRs (16 bank-balanced ds_read_b128), held across
        // the whole n-loop (lb(256,1) gives the register budget for this)
        float4 fr0[8], fr1[8];
#pragma unroll
        for (int jj = 0; jj < 8; ++jj) {
            fr0[jj] = WS[p][jj * 65 + c];
            fr1[jj] = WS[p][(8 + jj) * 65 + c];
        }

#pragma unroll
        for (int n = 0; n < NB; ++n) {
            const float4 xa = XS[p][(w * NB + n) * 2];       // broadcast reads
            const float4 xb = XS[p][(w * NB + n) * 2 + 1];

            float u[8];
#pragma unroll
            for (int jj = 0; jj < 8; ++jj) {
                float t = fr0[jj].x * xa.x;
                t = fmaf(fr0[jj].y, xa.y, t);
                t = fmaf(fr0[jj].z, xa.z, t);
                t = fmaf(fr0[jj].w, xa.w, t);
                t = fmaf(fr1[jj].x, xb.x, t);
                t = fmaf(fr1[jj].y, xb.y, t);
                t = fmaf(fr1[jj].z, xb.z, t);
                t = fmaf(fr1[jj].w, xb.w, t);
                u[jj] = t;
            }

            float cc;
            if (FIRST) {
                cc = 1.0f;   // softmax(0)=1/32 folded into epilogue scale
            } else {
                float bp = u[0] * va[n].x;
                bp = fmaf(u[1], va[n].y, bp);
                bp = fmaf(u[2], va[n].z, bp);
                bp = fmaf(u[3], va[n].w, bp);
                bp = fmaf(u[4], vb[n].x, bp);
                bp = fmaf(u[5], vb[n].y, bp);
                bp = fmaf(u[6], vb[n].z, bp);
                bp = fmaf(u[7], vb[n].w, bp);
                bp += __shfl_xor(bp, 32);          // combine j-halves
                const float e = __expf(bp);        // logits tiny; no max needed
                float se = e;
                se = dpp_add<0x128>(se);           // row_ror:8
                se = dpp_add<0x124>(se);           // row_ror:4
                se = dpp_add<0x122>(se);           // row_ror:2
                se = dpp_add<0x121>(se);           // row_ror:1
                se += __shfl_xor(se, 16);          // combine the two 16-rows
                cc = e * __builtin_amdgcn_rcpf(se);
            }
#pragma unroll
            for (int jj = 0; jj < 8; ++jj)
                acc[n][jj] = fmaf(cc, u[jj], acc[n][jj]);
        }

        // drain staged tile into the other parity (safe: top barrier of this
        // iteration guaranteed everyone finished reading p^1)
        if (more) {
            auto put = [&](int G, float4 val) {
                const int oo = G >> 5, j = (G >> 1) & 15, dh = G & 1;
                WS[p ^ 1][((dh << 3) | (j & 7)) * 65 + ((oo << 1) | (j >> 3))] = val;
            };
            put(0 * 256 + tid, g0);
            put(1 * 256 + tid, g1);
            put(2 * 256 + tid, g2);
            put(3 * 256 + tid, g3);
            if (tid < 64) XS[p ^ 1][tid] = gx;
        }
    }

    // ---- epilogue: dense full-line stores via LDS, 2 phases of 16 b.
    // Phase t: waves {2t, 2t+1} (owning b's t*16..t*16+15) deposit acc into
    // accred; all 4 waves then store 32 KB tid-contiguously (nontemporal).
    const float scale = FIRST ? (1.0f / 32.0f) : 1.0f;
#pragma unroll
    for (int t = 0; t < 2; ++t) {
        __syncthreads();   // previous phase / main-loop reads complete
        if ((w >> 1) == t) {
            const int bl0 = (w & 1) * NB;
#pragma unroll
            for (int n = 0; n < NB; ++n)
#pragma unroll
                for (int jj = 0; jj < 8; ++jj)
                    accred[(bl0 + n) * 520 + jj * 64 + c] = acc[n][jj] * scale;
        }
        __syncthreads();
        float* dstbase = part + (size_t)is * S_ELEMS + (size_t)(bblk + t * 16) * 512;
#pragma unroll
        for (int k = 0; k < 8; ++k) {
            const int q  = k * 256 + tid;        // quad 0..2047 (16 b x 512)
            const int e0 = q * 4;
            const int bl = e0 >> 9;
            const int oo = (e0 >> 4) & 31;
            const int j0 = e0 & 15;              // 4 consecutive j
            nt4 v;
            v.x = accred[bl * 520 + ((j0 + 0) & 7) * 64 + ((oo << 1) | ((j0 + 0) >> 3))];
            v.y = accred[bl * 520 + ((j0 + 1) & 7) * 64 + ((oo << 1) | ((j0 + 1) >> 3))];
            v.z = accred[bl * 520 + ((j0 + 2) & 7) * 64 + ((oo << 1) | ((j0 + 2) >> 3))];
            v.w = accred[bl * 520 + ((j0 + 3) & 7) * 64 + ((oo << 1) | ((j0 + 3) >> 3))];
            __builtin_nontemporal_store(v, (nt4*)(dstbase + e0));
        }
    }
}

// Fused 256-way partial reduction + squash, all fp32.
// MODE 0: vsum = v   MODE 1: vsum += v   MODE 2: out = v
template <int MODE>
__global__ void caps_reduce(const float* __restrict__ part,
                            float* __restrict__ vsum,
                            float* __restrict__ out)
{
    __shared__ float red[256];
    const int tid = threadIdx.x;
    const int e   = blockIdx.x * 64 + (tid & 63);   // (b,o,j) element
    const int ks  = tid >> 6;                       // k-slice 0..3
    float s = 0.0f;
#pragma unroll 8
    for (int m = 0; m < 64; ++m)
        s += __builtin_nontemporal_load(part + (size_t)(ks * 64 + m) * S_ELEMS + e);
    red[tid] = s;
    __syncthreads();
    if (tid < 64) {
        s = red[tid] + red[tid + 64] + red[tid + 128] + red[tid + 192];
        float s2 = s * s;                           // ||s||^2 over 16-j group
        s2 += __shfl_xor(s2, 1);
        s2 += __shfl_xor(s2, 2);
        s2 += __shfl_xor(s2, 4);
        s2 += __shfl_xor(s2, 8);
        const float v = s * (s2 / ((1.0f + s2) * sqrtf(s2 + 1e-9f)));
        if (MODE == 2)      out[e] = v;
        else if (MODE == 0) vsum[e] = v;
        else                vsum[e] += v;
    }
}

extern "C" void kernel_launch(void* const* d_in, const int* in_sizes, int n_in,
                              void* d_out, int out_size, void* d_ws, size_t ws_size,
                              hipStream_t stream)
{
    const float* x = (const float*)d_in[0];   // [64, 2048, 8]
    const float* W = (const float*)d_in[1];   // [1, 2048, 32, 16, 8]
    float* out = (float*)d_out;               // [64, 32, 16]

    float* part = (float*)d_ws;                    // 256 x 32768 x 4 B = 33.5 MB
    float* vsum = part + (size_t)ISTR * S_ELEMS;   // 32768 floats

    const dim3 g(BG * ISTR);       // 512 blocks
    const dim3 b(256);
    const dim3 rg(S_ELEMS / 64);   // 512 blocks

    caps_pass<1><<<g, b, 0, stream>>>(W, x, nullptr, part);
    caps_reduce<0><<<rg, b, 0, stream>>>(part, vsum, out);   // vsum = v0
    caps_pass<0><<<g, b, 0, stream>>>(W, x, vsum, part);
    caps_reduce<1><<<rg, b, 0, stream>>>(part, vsum, out);   // vsum = v0+v1
    caps_pass<0><<<g, b, 0, stream>>>(W, x, vsum, part);
    caps_reduce<2><<<rg, b, 0, stream>>>(part, vsum, out);   // out = v2
}